// Round 9
// baseline (1350.630 us; speedup 1.0000x reference)
//
#include <hip/hip_runtime.h>
#include <math.h>

#define HID    1024
#define GG     64
#define KPROP  5
#define H1     512
#define H2     256
#define NCLS   40
#define BNEPS  1e-5f
#define TILE   2048
#define BPART  128      // partition blocks for histogram/scatter
#define DSUP   512      // dst nodes per super-bucket (block)
#define DSH    9
#define STILE  2048     // src nodes per LDS tile
#define SSH    11
#define MAXCELL 12544   // >= NDS*NT for n <= ~114K (n=100000 -> 196*49=9604)

__host__ __device__ static inline int cdiv(int a, int b) { return (a + b - 1) / b; }

// ---------- Pass A: per-partition histogram of cell key = dstS*nt + srcT ----------
__global__ __launch_bounds__(1024) void k_hista(const int* __restrict__ row,
                                                const int* __restrict__ col,
                                                int* __restrict__ blockHist,
                                                int e, int ncell, int nt) {
    __shared__ int h[MAXCELL];
    for (int i = threadIdx.x; i < ncell; i += 1024) h[i] = 0;
    __syncthreads();
    int chunk = cdiv(e, gridDim.x);
    int s = blockIdx.x * chunk, t = min(e, s + chunk);
    for (int i = s + threadIdx.x; i < t; i += 1024) {
        int key = (col[i] >> DSH) * nt + (row[i] >> SSH);
        atomicAdd(&h[key], 1);
    }
    __syncthreads();
    for (int i = threadIdx.x; i < ncell; i += 1024)
        blockHist[(size_t)blockIdx.x * ncell + i] = h[i];
}

// ---------- Pass B: per-(partition,cell) offsets + exclusive cellPtr ----------
__global__ __launch_bounds__(1024) void k_scan(const int* __restrict__ blockHist,
                                               int* __restrict__ blockOff,
                                               int* __restrict__ cellPtr,
                                               int ncell, int e, int nbp) {
    __shared__ int psum[1024];
    int tid = threadIdx.x;
    // per-cell totals + per-partition exclusive offsets (strided = coalesced)
    for (int b = tid; b < ncell; b += 1024) {
        int s = 0;
        for (int p = 0; p < nbp; p++) {
            blockOff[(size_t)p * ncell + b] = s;
            s += blockHist[(size_t)p * ncell + b];
        }
        cellPtr[b] = s;                       // temp: per-cell total
    }
    __syncthreads();
    // chunked local sums
    int chunk = cdiv(ncell, 1024);
    int lo = tid * chunk, hi = min(ncell, lo + chunk);
    int loc = 0;
    for (int b = lo; b < hi; b++) loc += cellPtr[b];
    psum[tid] = loc;
    __syncthreads();
    // Hillis-Steele inclusive scan
    for (int off = 1; off < 1024; off <<= 1) {
        int add = (tid >= off) ? psum[tid - off] : 0;
        __syncthreads();
        psum[tid] += add;
        __syncthreads();
    }
    int run = (tid == 0) ? 0 : psum[tid - 1];
    for (int b = lo; b < hi; b++) { int v = cellPtr[b]; cellPtr[b] = run; run += v; }
    if (tid == 0) cellPtr[ncell] = e;
}

// ---------- Pass C: scatter packed edges into cell-sorted order ----------
// packed: src_local(11b) << 9 | dst_local(9b)
__global__ __launch_bounds__(1024) void k_scat(const int* __restrict__ row,
                                               const int* __restrict__ col,
                                               const int* __restrict__ blockOff,
                                               const int* __restrict__ cellPtr,
                                               int* __restrict__ ebuf,
                                               int e, int ncell, int nt) {
    __shared__ int c2[MAXCELL];
    for (int i = threadIdx.x; i < ncell; i += 1024) c2[i] = 0;
    __syncthreads();
    int chunk = cdiv(e, gridDim.x);
    int s = blockIdx.x * chunk, t = min(e, s + chunk);
    const int* boff = blockOff + (size_t)blockIdx.x * ncell;
    for (int i = s + threadIdx.x; i < t; i += 1024) {
        int r = row[i], c = col[i];
        int key = (c >> DSH) * nt + (r >> SSH);
        int lr = atomicAdd(&c2[key], 1);                 // LDS atomic — cheap
        int pos = cellPtr[key] + boff[key] + lr;         // globally unique
        ebuf[pos] = ((r & (STILE - 1)) << DSH) | (c & (DSUP - 1));
    }
}

// ---------- Pass D: per-bucket degree histogram + fused z0 init ----------
__global__ __launch_bounds__(512) void k_deg0(const int* __restrict__ cellPtr,
                                              const int* __restrict__ ebuf,
                                              int* __restrict__ deg,
                                              const float* __restrict__ pos,
                                              float4* __restrict__ z0, int n, int nt) {
    __shared__ int cnt[DSUP];
    int g = blockIdx.x, tid = threadIdx.x;
    cnt[tid] = 0;
    __syncthreads();
    int s0 = cellPtr[g * nt], s1 = cellPtr[(g + 1) * nt];  // bucket's cells contiguous
    for (int i = s0 + tid; i < s1; i += 512)
        atomicAdd(&cnt[ebuf[i] & (DSUP - 1)], 1);
    __syncthreads();
    int node = (g << DSH) + tid;
    if (node < n) {
        int d = cnt[tid];
        deg[node] = d;
        float dis = rsqrtf((float)(d + 1));
        z0[node] = make_float4(dis * pos[3 * node], dis * pos[3 * node + 1],
                               dis * pos[3 * node + 2], 0.f);
    }
}

// ---------- gather pass: tiled SpMM — coalesced z staging + LDS random reads ----------
// One block per dst super-bucket (512 nodes). Loop src tiles: stage 2048 float4
// (32 KB) coalesced, then process this cell's edges from LDS. No divergent L2
// requests — the R4..R8 wall (1 divergent req/cyc/XCD) is bypassed.
template <bool FINAL>
__global__ __launch_bounds__(512) void k_gtile(
    const int* __restrict__ ebuf, const int* __restrict__ cellPtr,
    const int* __restrict__ deg,
    const float4* __restrict__ zin, float4* __restrict__ zout,
    double* stats, int n, int nt) {
    __shared__ float4 zs[STILE];
    __shared__ float ax[DSUP], ay[DSUP], az[DSUP];
    int g = blockIdx.x, tid = threadIdx.x;
    ax[tid] = 0.f; ay[tid] = 0.f; az[tid] = 0.f;
    const int* cp = cellPtr + g * nt;
    for (int t = 0; t < nt; t++) {
        __syncthreads();                         // zs reuse + acc init visibility
        int base = t << SSH;
        int lim = min(STILE, n - base);
        for (int j = tid; j < lim; j += 512) zs[j] = zin[base + j];
        __syncthreads();
        int cs = cp[t], ce = cp[t + 1];
        for (int j = cs + tid; j < ce; j += 512) {
            int ev = ebuf[j];                    // coalesced
            float4 v = zs[ev >> DSH];            // random LDS read
            int d = ev & (DSUP - 1);
            atomicAdd(&ax[d], v.x);
            atomicAdd(&ay[d], v.y);
            atomicAdd(&az[d], v.z);
        }
    }
    __syncthreads();
    int node = (g << DSH) + tid;
    float x0 = 0.f, x1 = 0.f, x2 = 0.f;
    if (node < n) {
        float4 zi = zin[node];                   // self loop (coalesced)
        float dg = (float)(deg[node] + 1);
        float sc = FINAL ? rsqrtf(dg) : (1.0f / dg);
        x0 = sc * (ax[tid] + zi.x);
        x1 = sc * (ay[tid] + zi.y);
        x2 = sc * (az[tid] + zi.z);
        zout[node] = make_float4(x0, x1, x2, 0.f);
    }
    if (FINAL) {                                 // all 8 waves; OOB lanes add zeros
        double v[9];
        v[0] = x0; v[1] = x1; v[2] = x2;
        v[3] = (double)x0 * x0; v[4] = (double)x0 * x1; v[5] = (double)x0 * x2;
        v[6] = (double)x1 * x1; v[7] = (double)x1 * x2; v[8] = (double)x2 * x2;
#pragma unroll
        for (int jj = 0; jj < 9; jj++) {
            double s = v[jj];
            for (int m = 1; m < 64; m <<= 1) s += __shfl_xor(s, m, 64);
            if ((tid & 63) == 0) atomicAdd(&stats[jj], s);
        }
    }
}

// ---------- graph boundaries via binary search (batch is sorted) ----------
__global__ void k_bounds(const int* __restrict__ batch, int* starts, int n) {
    int g = threadIdx.x;
    if (g <= GG) {
        int lo = 0, hi = n;
        while (lo < hi) {
            int mid = (lo + hi) >> 1;
            if (batch[mid] < g) lo = mid + 1; else hi = mid;
        }
        starts[g] = lo;
    }
}

// ---------- pooling: per (graph, channel) max/min of dot(x, W_c), fused BN0+ReLU ----------
__global__ __launch_bounds__(256) void k_pool(
    const float4* __restrict__ z, const int* __restrict__ starts,
    const float* __restrict__ lin_w,
    const float* __restrict__ bn0_g, const float* __restrict__ bn0_b,
    const double* __restrict__ stats, float* pooled, int n) {
    __shared__ float4 sh[TILE];
    int g = blockIdx.x;
    int c = blockIdx.y * 256 + threadIdx.x;

    float w0 = lin_w[c], w1 = lin_w[HID + c], w2 = lin_w[2 * HID + c];

    double invN = 1.0 / (double)n;
    double mu0 = stats[0] * invN, mu1 = stats[1] * invN, mu2 = stats[2] * invN;
    float c00 = (float)(stats[3] * invN - mu0 * mu0);
    float c01 = (float)(stats[4] * invN - mu0 * mu1);
    float c02 = (float)(stats[5] * invN - mu0 * mu2);
    float c11 = (float)(stats[6] * invN - mu1 * mu1);
    float c12 = (float)(stats[7] * invN - mu1 * mu2);
    float c22 = (float)(stats[8] * invN - mu2 * mu2);
    float meanc = (float)mu0 * w0 + (float)mu1 * w1 + (float)mu2 * w2;  // lin_b cancels in BN
    float var = c00 * w0 * w0 + c11 * w1 * w1 + c22 * w2 * w2
              + 2.f * (c01 * w0 * w1 + c02 * w0 * w2 + c12 * w1 * w2);
    var = fmaxf(var, 0.f);

    int s0 = starts[g], s1 = starts[g + 1];
    float mx = -INFINITY, mn = INFINITY;
    for (int base = s0; base < s1; base += TILE) {
        int cnt = min(TILE, s1 - base);
        __syncthreads();
        for (int j = threadIdx.x; j < cnt; j += 256) sh[j] = z[base + j];
        __syncthreads();
        for (int j = 0; j < cnt; j++) {
            float4 p = sh[j];
            float d = fmaf(p.x, w0, fmaf(p.y, w1, p.z * w2));
            mx = fmaxf(mx, d);
            mn = fminf(mn, d);
        }
    }
    float inv = rsqrtf(var + BNEPS);
    float s = bn0_g[c] * inv;
    float raw = (s >= 0.f) ? mx : mn;     // BN scale sign decides which extreme survives relu∘max
    float y = (raw - meanc) * s + bn0_b[c];
    pooled[g * HID + c] = fmaxf(y, 0.f);
}

// ---------- fused Linear + BN(over 64 rows = 1 wave) + ReLU; 1 wave per output column ----------
template <int KIN>
__global__ __launch_bounds__(64) void k_fcbn(
    const float* __restrict__ in, const float* __restrict__ W,
    const float* __restrict__ bias, const float* __restrict__ gamma,
    const float* __restrict__ beta, float* out, int Cout) {
    int c = blockIdx.x;
    int r = threadIdx.x;  // 64 rows == wave size
    const float* rowp = in + r * KIN;
    float acc = 0.f;
#pragma unroll 8
    for (int k = 0; k < KIN; k++) acc = fmaf(rowp[k], W[k * Cout + c], acc);
    float y = acc + bias[c];
    float sum = y, sq = y * y;
    for (int m = 1; m < 64; m <<= 1) {
        sum += __shfl_xor(sum, m, 64);
        sq  += __shfl_xor(sq, m, 64);
    }
    float mean = sum * (1.f / 64.f);
    float var  = fmaxf(sq * (1.f / 64.f) - mean * mean, 0.f);
    float o = (y - mean) * rsqrtf(var + BNEPS) * gamma[c] + beta[c];
    out[r * Cout + c] = fmaxf(o, 0.f);
}

// ---------- fc3 + log_softmax; 1 wave per row ----------
__global__ __launch_bounds__(64) void k_out(
    const float* __restrict__ in, const float* __restrict__ W,
    const float* __restrict__ bias, float* out) {
    int r = blockIdx.x;
    int c = threadIdx.x;
    bool act = c < NCLS;
    float z = -INFINITY;
    if (act) {
        const float* rowp = in + r * H2;
        float acc = 0.f;
#pragma unroll 8
        for (int k = 0; k < H2; k++) acc = fmaf(rowp[k], W[k * NCLS + c], acc);
        z = acc + bias[c];
    }
    float mx = z;
    for (int m = 1; m < 64; m <<= 1) mx = fmaxf(mx, __shfl_xor(mx, m, 64));
    float ex = act ? expf(z - mx) : 0.f;
    float se = ex;
    for (int m = 1; m < 64; m <<= 1) se += __shfl_xor(se, m, 64);
    if (act) out[r * NCLS + c] = z - mx - logf(se);
}

extern "C" void kernel_launch(void* const* d_in, const int* in_sizes, int n_in,
                              void* d_out, int out_size, void* d_ws, size_t ws_size,
                              hipStream_t stream) {
    const float* pos   = (const float*)d_in[0];
    const int*   ei    = (const int*)d_in[1];   // [2,E]: rows at [0,E), cols at [E,2E)
    const int*   batch = (const int*)d_in[2];
    const float* lin_w = (const float*)d_in[3];
    // d_in[4] lin_b cancels in BN0 centering
    const float* bn0_g = (const float*)d_in[5];
    const float* bn0_b = (const float*)d_in[6];
    const float* fc1_w = (const float*)d_in[7];
    const float* fc1_b = (const float*)d_in[8];
    const float* bn1_g = (const float*)d_in[9];
    const float* bn1_b = (const float*)d_in[10];
    const float* fc2_w = (const float*)d_in[11];
    const float* fc2_b = (const float*)d_in[12];
    const float* bn2_g = (const float*)d_in[13];
    const float* bn2_b = (const float*)d_in[14];
    const float* fc3_w = (const float*)d_in[15];
    const float* fc3_b = (const float*)d_in[16];

    int n = in_sizes[0] / 3;
    int e = in_sizes[1] / 2;
    int nds = cdiv(n, DSUP);       // 196 for n=100000
    int nt  = cdiv(n, STILE);      // 49
    int ncell = nds * nt;          // 9604 (<= MAXCELL)

    auto align256 = [](size_t x) { return (x + 255) & ~(size_t)255; };
    char* w = (char*)d_ws;
    int*    blockHist = (int*)w;    w += align256((size_t)BPART * ncell * 4);
    int*    blockOff  = (int*)w;    w += align256((size_t)BPART * ncell * 4);
    int*    cellPtr   = (int*)w;    w += align256((size_t)(ncell + 1) * 4);
    int*    deg       = (int*)w;    w += align256((size_t)n * 4);
    int*    ebuf      = (int*)w;    w += align256((size_t)e * 4);
    float4* za        = (float4*)w; w += align256((size_t)n * 16);
    float4* zb        = (float4*)w; w += align256((size_t)n * 16);
    double* stats     = (double*)w; w += align256(9 * sizeof(double));
    int*    starts    = (int*)w;    w += align256((GG + 1) * 4);
    float*  pooled    = (float*)w;  w += align256((size_t)GG * HID * 4);
    float*  h1        = (float*)w;  w += align256((size_t)GG * H1 * 4);
    float*  h2        = (float*)w;  w += align256((size_t)GG * H2 * 4);

    (void)hipMemsetAsync(stats, 0, 9 * sizeof(double), stream);

    const int* erow = ei;
    const int* ecol = ei + e;

    k_hista<<<BPART, 1024, 0, stream>>>(erow, ecol, blockHist, e, ncell, nt);
    k_scan <<<1, 1024, 0, stream>>>(blockHist, blockOff, cellPtr, ncell, e, BPART);
    k_scat <<<BPART, 1024, 0, stream>>>(erow, ecol, blockOff, cellPtr, ebuf, e, ncell, nt);
    k_deg0 <<<nds, 512, 0, stream>>>(cellPtr, ebuf, deg, pos, za, n, nt);

    // K=5 passes, double-buffered: za->zb->za->zb->za->zb (final in zb)
    k_gtile<false><<<nds, 512, 0, stream>>>(ebuf, cellPtr, deg, za, zb, stats, n, nt);
    k_gtile<false><<<nds, 512, 0, stream>>>(ebuf, cellPtr, deg, zb, za, stats, n, nt);
    k_gtile<false><<<nds, 512, 0, stream>>>(ebuf, cellPtr, deg, za, zb, stats, n, nt);
    k_gtile<false><<<nds, 512, 0, stream>>>(ebuf, cellPtr, deg, zb, za, stats, n, nt);
    k_gtile<true ><<<nds, 512, 0, stream>>>(ebuf, cellPtr, deg, za, zb, stats, n, nt);

    k_bounds<<<1, 128, 0, stream>>>(batch, starts, n);
    k_pool<<<dim3(GG, HID / 256), 256, 0, stream>>>(zb, starts, lin_w, bn0_g, bn0_b, stats, pooled, n);
    k_fcbn<HID><<<H1, 64, 0, stream>>>(pooled, fc1_w, fc1_b, bn1_g, bn1_b, h1, H1);
    k_fcbn<H1><<<H2, 64, 0, stream>>>(h1, fc2_w, fc2_b, bn2_g, bn2_b, h2, H2);
    k_out<<<GG, 64, 0, stream>>>(h2, fc3_w, fc3_b, (float*)d_out);
}

// Round 10
// 982.584 us; speedup vs baseline: 1.3746x; 1.3746x over previous
//
#include <hip/hip_runtime.h>
#include <math.h>

#define HID    1024
#define GG     64
#define KPROP  5
#define H1     512
#define H2     256
#define NCLS   40
#define BNEPS  1e-5f
#define TILE   2048
#define BPART  128      // partition blocks for histogram/scatter
#define DSUP   512      // dst nodes per bucket (block)
#define DSH    9
#define STILE  2048     // src nodes per LDS tile
#define SSH    11
#define MAXNDS 256      // supports n <= 131072
#define MAXNT  64

__host__ __device__ static inline int cdiv(int a, int b) { return (a + b - 1) / b; }

// ---------- Pass A: per-partition histogram over dst buckets ----------
__global__ __launch_bounds__(1024) void k_hista(const int* __restrict__ col,
                                                int* __restrict__ blockHist,
                                                int e, int nds) {
    __shared__ int h[MAXNDS];
    if (threadIdx.x < nds) h[threadIdx.x] = 0;
    __syncthreads();
    int chunk = cdiv(e, gridDim.x);
    int s = blockIdx.x * chunk, t = min(e, s + chunk);
    for (int i = s + threadIdx.x; i < t; i += 1024) atomicAdd(&h[col[i] >> DSH], 1);
    __syncthreads();
    if (threadIdx.x < nds) blockHist[blockIdx.x * nds + threadIdx.x] = h[threadIdx.x];
}

// ---------- Pass B: per-(partition,bucket) offsets + bucket starts ----------
__global__ __launch_bounds__(256) void k_scan(const int* __restrict__ blockHist,
                                              int* __restrict__ blockOff,
                                              int* __restrict__ bucketStart,
                                              int e, int nds) {
    __shared__ int tot[MAXNDS];
    int bin = threadIdx.x;
    if (bin < nds) {
        int s = 0;
        for (int p = 0; p < BPART; p++) {
            blockOff[p * nds + bin] = s;    // coalesced across threads
            s += blockHist[p * nds + bin];
        }
        tot[bin] = s;
    }
    __syncthreads();
    if (bin == 0) {
        int acc = 0;
        for (int i = 0; i < nds; i++) { int v = tot[i]; tot[i] = acc; acc += v; }
    }
    __syncthreads();
    if (bin < nds) bucketStart[bin] = tot[bin];
    if (bin == 0) bucketStart[nds] = e;
}

// ---------- Pass C: scatter packed edges into dst-bucket order ----------
// runs of ~e/(nds*BPART) ~= 127 edges per (partition,bucket) -> coalesced writes.
// packed: tile(6b) << 20 | src_local(11b) << 9 | dst_local(9b)
__global__ __launch_bounds__(1024) void k_scat(const int* __restrict__ row,
                                               const int* __restrict__ col,
                                               const int* __restrict__ blockOff,
                                               const int* __restrict__ bucketStart,
                                               int* __restrict__ ebuf1,
                                               int e, int nds) {
    __shared__ int c2[MAXNDS];
    if (threadIdx.x < nds) c2[threadIdx.x] = 0;
    __syncthreads();
    int chunk = cdiv(e, gridDim.x);
    int s = blockIdx.x * chunk, t = min(e, s + chunk);
    const int* boff = blockOff + blockIdx.x * nds;
    for (int i = s + threadIdx.x; i < t; i += 1024) {
        int r = row[i], c = col[i];
        int bin = c >> DSH;
        int lr = atomicAdd(&c2[bin], 1);                  // LDS atomic — cheap
        int pos = bucketStart[bin] + boff[bin] + lr;      // globally unique
        ebuf1[pos] = ((r >> SSH) << 20) | ((r & (STILE - 1)) << DSH) | (c & (DSUP - 1));
    }
}

// ---------- Pass D: per-bucket tile-sort (ebuf1 -> ebuf2) + cellPtr + deg + z0 ----------
__global__ __launch_bounds__(512) void k_tsort(const int* __restrict__ bucketStart,
                                               const int* __restrict__ ebuf1,
                                               int* __restrict__ ebuf2,
                                               int* __restrict__ cellPtr,
                                               int* __restrict__ deg,
                                               const float* __restrict__ pos,
                                               float4* __restrict__ z0,
                                               int n, int nt) {
    __shared__ int cnt[MAXNT];
    __shared__ int lptr[MAXNT + 1];
    __shared__ int dcnt[DSUP];
    int g = blockIdx.x, tid = threadIdx.x;
    if (tid < nt) cnt[tid] = 0;
    dcnt[tid] = 0;
    __syncthreads();
    int s0 = bucketStart[g], s1 = bucketStart[g + 1];
    for (int i = s0 + tid; i < s1; i += 512) {
        int v = ebuf1[i];
        atomicAdd(&cnt[v >> 20], 1);
        atomicAdd(&dcnt[v & (DSUP - 1)], 1);
    }
    __syncthreads();
    if (tid == 0) {
        int acc = 0;
        for (int i = 0; i < nt; i++) { lptr[i] = acc; acc += cnt[i]; }
        lptr[nt] = acc;
    }
    __syncthreads();
    if (tid <= nt) cellPtr[g * (nt + 1) + tid] = s0 + lptr[tid];
    int node = (g << DSH) + tid;
    if (node < n) {
        int d = dcnt[tid];
        deg[node] = d;
        float dis = rsqrtf((float)(d + 1));
        z0[node] = make_float4(dis * pos[3 * node], dis * pos[3 * node + 1],
                               dis * pos[3 * node + 2], 0.f);
    }
    if (tid < nt) cnt[tid] = 0;
    __syncthreads();
    for (int i = s0 + tid; i < s1; i += 512) {
        int v = ebuf1[i];
        int t = v >> 20;
        int r = atomicAdd(&cnt[t], 1);
        ebuf2[s0 + lptr[t] + r] = v & 0xFFFFF;   // keep src_local|dst_local
    }
}

// ---------- gather pass: tiled SpMM — coalesced z staging + LDS random reads ----------
// (R9-proven: bypasses the divergent-L2-request wall of R4..R8)
template <bool FINAL>
__global__ __launch_bounds__(512) void k_gtile(
    const int* __restrict__ ebuf, const int* __restrict__ cellPtr,
    const int* __restrict__ deg,
    const float4* __restrict__ zin, float4* __restrict__ zout,
    double* stats, int n, int nt) {
    __shared__ float4 zs[STILE];
    __shared__ float ax[DSUP], ay[DSUP], az[DSUP];
    int g = blockIdx.x, tid = threadIdx.x;
    ax[tid] = 0.f; ay[tid] = 0.f; az[tid] = 0.f;
    const int* cp = cellPtr + g * (nt + 1);
    for (int t = 0; t < nt; t++) {
        __syncthreads();                         // zs reuse + acc visibility
        int base = t << SSH;
        int lim = min(STILE, n - base);
        for (int j = tid; j < lim; j += 512) zs[j] = zin[base + j];
        __syncthreads();
        int cs = cp[t], ce = cp[t + 1];
        for (int j = cs + tid; j < ce; j += 512) {
            int ev = ebuf[j];                    // coalesced
            float4 v = zs[ev >> DSH];            // random LDS read
            int d = ev & (DSUP - 1);
            atomicAdd(&ax[d], v.x);
            atomicAdd(&ay[d], v.y);
            atomicAdd(&az[d], v.z);
        }
    }
    __syncthreads();
    int node = (g << DSH) + tid;
    float x0 = 0.f, x1 = 0.f, x2 = 0.f;
    if (node < n) {
        float4 zi = zin[node];                   // self loop (coalesced)
        float dg = (float)(deg[node] + 1);
        float sc = FINAL ? rsqrtf(dg) : (1.0f / dg);
        x0 = sc * (ax[tid] + zi.x);
        x1 = sc * (ay[tid] + zi.y);
        x2 = sc * (az[tid] + zi.z);
        zout[node] = make_float4(x0, x1, x2, 0.f);
    }
    if (FINAL) {                                 // OOB lanes contribute zeros
        double v[9];
        v[0] = x0; v[1] = x1; v[2] = x2;
        v[3] = (double)x0 * x0; v[4] = (double)x0 * x1; v[5] = (double)x0 * x2;
        v[6] = (double)x1 * x1; v[7] = (double)x1 * x2; v[8] = (double)x2 * x2;
#pragma unroll
        for (int jj = 0; jj < 9; jj++) {
            double s = v[jj];
            for (int m = 1; m < 64; m <<= 1) s += __shfl_xor(s, m, 64);
            if ((tid & 63) == 0) atomicAdd(&stats[jj], s);
        }
    }
}

// ---------- graph boundaries via binary search (batch is sorted) ----------
__global__ void k_bounds(const int* __restrict__ batch, int* starts, int n) {
    int g = threadIdx.x;
    if (g <= GG) {
        int lo = 0, hi = n;
        while (lo < hi) {
            int mid = (lo + hi) >> 1;
            if (batch[mid] < g) lo = mid + 1; else hi = mid;
        }
        starts[g] = lo;
    }
}

// ---------- pooling: per (graph, channel) max/min of dot(x, W_c), fused BN0+ReLU ----------
__global__ __launch_bounds__(256) void k_pool(
    const float4* __restrict__ z, const int* __restrict__ starts,
    const float* __restrict__ lin_w,
    const float* __restrict__ bn0_g, const float* __restrict__ bn0_b,
    const double* __restrict__ stats, float* pooled, int n) {
    __shared__ float4 sh[TILE];
    int g = blockIdx.x;
    int c = blockIdx.y * 256 + threadIdx.x;

    float w0 = lin_w[c], w1 = lin_w[HID + c], w2 = lin_w[2 * HID + c];

    double invN = 1.0 / (double)n;
    double mu0 = stats[0] * invN, mu1 = stats[1] * invN, mu2 = stats[2] * invN;
    float c00 = (float)(stats[3] * invN - mu0 * mu0);
    float c01 = (float)(stats[4] * invN - mu0 * mu1);
    float c02 = (float)(stats[5] * invN - mu0 * mu2);
    float c11 = (float)(stats[6] * invN - mu1 * mu1);
    float c12 = (float)(stats[7] * invN - mu1 * mu2);
    float c22 = (float)(stats[8] * invN - mu2 * mu2);
    float meanc = (float)mu0 * w0 + (float)mu1 * w1 + (float)mu2 * w2;  // lin_b cancels in BN
    float var = c00 * w0 * w0 + c11 * w1 * w1 + c22 * w2 * w2
              + 2.f * (c01 * w0 * w1 + c02 * w0 * w2 + c12 * w1 * w2);
    var = fmaxf(var, 0.f);

    int s0 = starts[g], s1 = starts[g + 1];
    float mx = -INFINITY, mn = INFINITY;
    for (int base = s0; base < s1; base += TILE) {
        int cnt = min(TILE, s1 - base);
        __syncthreads();
        for (int j = threadIdx.x; j < cnt; j += 256) sh[j] = z[base + j];
        __syncthreads();
        for (int j = 0; j < cnt; j++) {
            float4 p = sh[j];
            float d = fmaf(p.x, w0, fmaf(p.y, w1, p.z * w2));
            mx = fmaxf(mx, d);
            mn = fminf(mn, d);
        }
    }
    float inv = rsqrtf(var + BNEPS);
    float s = bn0_g[c] * inv;
    float raw = (s >= 0.f) ? mx : mn;     // BN scale sign decides which extreme survives relu∘max
    float y = (raw - meanc) * s + bn0_b[c];
    pooled[g * HID + c] = fmaxf(y, 0.f);
}

// ---------- fused Linear + BN(over 64 rows = 1 wave) + ReLU; 1 wave per output column ----------
template <int KIN>
__global__ __launch_bounds__(64) void k_fcbn(
    const float* __restrict__ in, const float* __restrict__ W,
    const float* __restrict__ bias, const float* __restrict__ gamma,
    const float* __restrict__ beta, float* out, int Cout) {
    int c = blockIdx.x;
    int r = threadIdx.x;  // 64 rows == wave size
    const float* rowp = in + r * KIN;
    float acc = 0.f;
#pragma unroll 8
    for (int k = 0; k < KIN; k++) acc = fmaf(rowp[k], W[k * Cout + c], acc);
    float y = acc + bias[c];
    float sum = y, sq = y * y;
    for (int m = 1; m < 64; m <<= 1) {
        sum += __shfl_xor(sum, m, 64);
        sq  += __shfl_xor(sq, m, 64);
    }
    float mean = sum * (1.f / 64.f);
    float var  = fmaxf(sq * (1.f / 64.f) - mean * mean, 0.f);
    float o = (y - mean) * rsqrtf(var + BNEPS) * gamma[c] + beta[c];
    out[r * Cout + c] = fmaxf(o, 0.f);
}

// ---------- fc3 + log_softmax; 1 wave per row ----------
__global__ __launch_bounds__(64) void k_out(
    const float* __restrict__ in, const float* __restrict__ W,
    const float* __restrict__ bias, float* out) {
    int r = blockIdx.x;
    int c = threadIdx.x;
    bool act = c < NCLS;
    float z = -INFINITY;
    if (act) {
        const float* rowp = in + r * H2;
        float acc = 0.f;
#pragma unroll 8
        for (int k = 0; k < H2; k++) acc = fmaf(rowp[k], W[k * NCLS + c], acc);
        z = acc + bias[c];
    }
    float mx = z;
    for (int m = 1; m < 64; m <<= 1) mx = fmaxf(mx, __shfl_xor(mx, m, 64));
    float ex = act ? expf(z - mx) : 0.f;
    float se = ex;
    for (int m = 1; m < 64; m <<= 1) se += __shfl_xor(se, m, 64);
    if (act) out[r * NCLS + c] = z - mx - logf(se);
}

extern "C" void kernel_launch(void* const* d_in, const int* in_sizes, int n_in,
                              void* d_out, int out_size, void* d_ws, size_t ws_size,
                              hipStream_t stream) {
    const float* pos   = (const float*)d_in[0];
    const int*   ei    = (const int*)d_in[1];   // [2,E]: rows at [0,E), cols at [E,2E)
    const int*   batch = (const int*)d_in[2];
    const float* lin_w = (const float*)d_in[3];
    // d_in[4] lin_b cancels in BN0 centering
    const float* bn0_g = (const float*)d_in[5];
    const float* bn0_b = (const float*)d_in[6];
    const float* fc1_w = (const float*)d_in[7];
    const float* fc1_b = (const float*)d_in[8];
    const float* bn1_g = (const float*)d_in[9];
    const float* bn1_b = (const float*)d_in[10];
    const float* fc2_w = (const float*)d_in[11];
    const float* fc2_b = (const float*)d_in[12];
    const float* bn2_g = (const float*)d_in[13];
    const float* bn2_b = (const float*)d_in[14];
    const float* fc3_w = (const float*)d_in[15];
    const float* fc3_b = (const float*)d_in[16];

    int n = in_sizes[0] / 3;
    int e = in_sizes[1] / 2;
    int nds = cdiv(n, DSUP);       // 196 for n=100000
    int nt  = cdiv(n, STILE);      // 49

    auto align256 = [](size_t x) { return (x + 255) & ~(size_t)255; };
    char* w = (char*)d_ws;
    int*    blockHist = (int*)w;    w += align256((size_t)BPART * nds * 4);
    int*    blockOff  = (int*)w;    w += align256((size_t)BPART * nds * 4);
    int*    bucketSt  = (int*)w;    w += align256((size_t)(nds + 1) * 4);
    int*    cellPtr   = (int*)w;    w += align256((size_t)nds * (nt + 1) * 4);
    int*    deg       = (int*)w;    w += align256((size_t)n * 4);
    int*    ebuf1     = (int*)w;    w += align256((size_t)e * 4);
    int*    ebuf2     = (int*)w;    w += align256((size_t)e * 4);
    float4* za        = (float4*)w; w += align256((size_t)n * 16);
    float4* zb        = (float4*)w; w += align256((size_t)n * 16);
    double* stats     = (double*)w; w += align256(9 * sizeof(double));
    int*    starts    = (int*)w;    w += align256((GG + 1) * 4);
    float*  pooled    = (float*)w;  w += align256((size_t)GG * HID * 4);
    float*  h1        = (float*)w;  w += align256((size_t)GG * H1 * 4);
    float*  h2        = (float*)w;  w += align256((size_t)GG * H2 * 4);

    (void)hipMemsetAsync(stats, 0, 9 * sizeof(double), stream);

    const int* erow = ei;
    const int* ecol = ei + e;

    k_hista<<<BPART, 1024, 0, stream>>>(ecol, blockHist, e, nds);
    k_scan <<<1, 256, 0, stream>>>(blockHist, blockOff, bucketSt, e, nds);
    k_scat <<<BPART, 1024, 0, stream>>>(erow, ecol, blockOff, bucketSt, ebuf1, e, nds);
    k_tsort<<<nds, 512, 0, stream>>>(bucketSt, ebuf1, ebuf2, cellPtr, deg, pos, za, n, nt);

    // K=5 passes, double-buffered: za->zb->za->zb->za->zb (final in zb)
    k_gtile<false><<<nds, 512, 0, stream>>>(ebuf2, cellPtr, deg, za, zb, stats, n, nt);
    k_gtile<false><<<nds, 512, 0, stream>>>(ebuf2, cellPtr, deg, zb, za, stats, n, nt);
    k_gtile<false><<<nds, 512, 0, stream>>>(ebuf2, cellPtr, deg, za, zb, stats, n, nt);
    k_gtile<false><<<nds, 512, 0, stream>>>(ebuf2, cellPtr, deg, zb, za, stats, n, nt);
    k_gtile<true ><<<nds, 512, 0, stream>>>(ebuf2, cellPtr, deg, za, zb, stats, n, nt);

    k_bounds<<<1, 128, 0, stream>>>(batch, starts, n);
    k_pool<<<dim3(GG, HID / 256), 256, 0, stream>>>(zb, starts, lin_w, bn0_g, bn0_b, stats, pooled, n);
    k_fcbn<HID><<<H1, 64, 0, stream>>>(pooled, fc1_w, fc1_b, bn1_g, bn1_b, h1, H1);
    k_fcbn<H1><<<H2, 64, 0, stream>>>(h1, fc2_w, fc2_b, bn2_g, bn2_b, h2, H2);
    k_out<<<GG, 64, 0, stream>>>(h2, fc3_w, fc3_b, (float*)d_out);
}

// Round 11
// 841.294 us; speedup vs baseline: 1.6054x; 1.1679x over previous
//
#include <hip/hip_runtime.h>
#include <math.h>

#define HID    1024
#define GG     64
#define KPROP  5
#define H1     512
#define H2     256
#define NCLS   40
#define BNEPS  1e-5f
#define TILE   2048
#define BPART  128      // partition blocks for histogram/scatter
#define DSUP   512      // dst nodes per bucket
#define DSH    9
#define STILE  1024     // src nodes per LDS tile
#define SSH    10
#define TCH    7        // tile-chunks per bucket (parallelism multiplier)
#define MAXNDS 256      // supports n <= 131072
#define MAXNT  128

__host__ __device__ static inline int cdiv(int a, int b) { return (a + b - 1) / b; }

// ---------- Pass A: per-partition histogram over dst buckets ----------
__global__ __launch_bounds__(1024) void k_hista(const int* __restrict__ col,
                                                int* __restrict__ blockHist,
                                                int e, int nds) {
    __shared__ int h[MAXNDS];
    if (threadIdx.x < nds) h[threadIdx.x] = 0;
    __syncthreads();
    int chunk = cdiv(e, gridDim.x);
    int s = blockIdx.x * chunk, t = min(e, s + chunk);
    for (int i = s + threadIdx.x; i < t; i += 1024) atomicAdd(&h[col[i] >> DSH], 1);
    __syncthreads();
    if (threadIdx.x < nds) blockHist[blockIdx.x * nds + threadIdx.x] = h[threadIdx.x];
}

// ---------- Pass B: per-(partition,bucket) offsets + bucket starts ----------
__global__ __launch_bounds__(256) void k_scan(const int* __restrict__ blockHist,
                                              int* __restrict__ blockOff,
                                              int* __restrict__ bucketStart,
                                              int e, int nds) {
    __shared__ int tot[MAXNDS];
    int bin = threadIdx.x;
    if (bin < nds) {
        int s = 0;
        for (int p = 0; p < BPART; p++) {
            blockOff[p * nds + bin] = s;    // coalesced across threads
            s += blockHist[p * nds + bin];
        }
        tot[bin] = s;
    }
    __syncthreads();
    if (bin == 0) {
        int acc = 0;
        for (int i = 0; i < nds; i++) { int v = tot[i]; tot[i] = acc; acc += v; }
    }
    __syncthreads();
    if (bin < nds) bucketStart[bin] = tot[bin];
    if (bin == 0) bucketStart[nds] = e;
}

// ---------- Pass C: scatter packed edges into dst-bucket order ----------
// runs of ~e/(nds*BPART) ~= 127 edges per (partition,bucket) -> coalesced writes.
// packed: tile(7b) << 19 | src_local(10b) << 9 | dst_local(9b)
__global__ __launch_bounds__(1024) void k_scat(const int* __restrict__ row,
                                               const int* __restrict__ col,
                                               const int* __restrict__ blockOff,
                                               const int* __restrict__ bucketStart,
                                               int* __restrict__ ebuf1,
                                               int e, int nds) {
    __shared__ int c2[MAXNDS];
    if (threadIdx.x < nds) c2[threadIdx.x] = 0;
    __syncthreads();
    int chunk = cdiv(e, gridDim.x);
    int s = blockIdx.x * chunk, t = min(e, s + chunk);
    const int* boff = blockOff + blockIdx.x * nds;
    for (int i = s + threadIdx.x; i < t; i += 1024) {
        int r = row[i], c = col[i];
        int bin = c >> DSH;
        int lr = atomicAdd(&c2[bin], 1);                  // LDS atomic — cheap
        int pos = bucketStart[bin] + boff[bin] + lr;      // globally unique
        ebuf1[pos] = ((r >> SSH) << 19) | ((r & (STILE - 1)) << DSH) | (c & (DSUP - 1));
    }
}

// ---------- Pass D: per-bucket tile-sort (ebuf1 -> ebuf2) + cellPtr + deg + z0 ----------
__global__ __launch_bounds__(512) void k_tsort(const int* __restrict__ bucketStart,
                                               const int* __restrict__ ebuf1,
                                               int* __restrict__ ebuf2,
                                               int* __restrict__ cellPtr,
                                               int* __restrict__ deg,
                                               const float* __restrict__ pos,
                                               float4* __restrict__ z0,
                                               int n, int nt) {
    __shared__ int cnt[MAXNT];
    __shared__ int lptr[MAXNT + 1];
    __shared__ int dcnt[DSUP];
    int g = blockIdx.x, tid = threadIdx.x;
    if (tid < nt) cnt[tid] = 0;
    dcnt[tid] = 0;
    __syncthreads();
    int s0 = bucketStart[g], s1 = bucketStart[g + 1];
    for (int i = s0 + tid; i < s1; i += 512) {
        int v = ebuf1[i];
        atomicAdd(&cnt[v >> 19], 1);
        atomicAdd(&dcnt[v & (DSUP - 1)], 1);
    }
    __syncthreads();
    if (tid == 0) {
        int acc = 0;
        for (int i = 0; i < nt; i++) { lptr[i] = acc; acc += cnt[i]; }
        lptr[nt] = acc;
    }
    __syncthreads();
    if (tid <= nt) cellPtr[g * (nt + 1) + tid] = s0 + lptr[tid];
    int node = (g << DSH) + tid;
    if (node < n) {
        int d = dcnt[tid];
        deg[node] = d;
        float dis = rsqrtf((float)(d + 1));
        z0[node] = make_float4(dis * pos[3 * node], dis * pos[3 * node + 1],
                               dis * pos[3 * node + 2], 0.f);
    }
    if (tid < nt) cnt[tid] = 0;
    __syncthreads();
    for (int i = s0 + tid; i < s1; i += 512) {
        int v = ebuf1[i];
        int t = v >> 19;
        int r = atomicAdd(&cnt[t], 1);
        ebuf2[s0 + lptr[t] + r] = v & 0x7FFFF;   // keep src_local|dst_local
    }
}

// ---------- gather partial: (bucket, tile-chunk) blocks — tiled SpMM in LDS ----------
// 1372 blocks, 22 KB LDS -> 4 blocks/CU, 32 waves/CU: fixes R10's 196-block
// serialization while keeping the no-divergent-L2 property.
__global__ __launch_bounds__(512) void k_gpart(
    const int* __restrict__ ebuf, const int* __restrict__ cellPtr,
    const float4* __restrict__ zin, float4* __restrict__ partial,
    int n, int nt, int csz, int nds) {
    __shared__ float4 zs[STILE];
    __shared__ float ax[DSUP], ay[DSUP], az[DSUP];
    int g = blockIdx.x, ci = blockIdx.y, tid = threadIdx.x;
    ax[tid] = 0.f; ay[tid] = 0.f; az[tid] = 0.f;
    const int* cp = cellPtr + g * (nt + 1);
    int t0 = ci * csz, t1 = min(nt, t0 + csz);
    for (int t = t0; t < t1; t++) {
        __syncthreads();                         // zs reuse + acc visibility
        int base = t << SSH;
        int lim = min(STILE, n - base);
        for (int j = tid; j < lim; j += 512) zs[j] = zin[base + j];
        __syncthreads();
        int cs = cp[t], ce = cp[t + 1];
        for (int j = cs + tid; j < ce; j += 512) {
            int ev = ebuf[j];                    // coalesced
            float4 v = zs[(ev >> DSH) & (STILE - 1)];  // random LDS read
            int d = ev & (DSUP - 1);
            atomicAdd(&ax[d], v.x);
            atomicAdd(&ay[d], v.y);
            atomicAdd(&az[d], v.z);
        }
    }
    __syncthreads();
    partial[((size_t)(ci * nds + g) << DSH) + tid] =
        make_float4(ax[tid], ay[tid], az[tid], 0.f);
}

// ---------- fold partials + self-loop + scale; FINAL adds moment reduction ----------
template <bool FINAL>
__global__ __launch_bounds__(256) void k_reduce(
    const float4* __restrict__ partial, const float4* __restrict__ zin,
    const int* __restrict__ deg, float4* __restrict__ zout,
    double* stats, int n, int nds, int tch) {
    int node = blockIdx.x * 256 + threadIdx.x;
    float x0 = 0.f, x1 = 0.f, x2 = 0.f;
    if (node < n) {
        int g = node >> DSH, l = node & (DSUP - 1);
        float4 zi = zin[node];                   // self loop
        float s0 = zi.x, s1 = zi.y, s2 = zi.z;
        for (int ci = 0; ci < tch; ci++) {       // coalesced within each ci
            float4 p = partial[((size_t)(ci * nds + g) << DSH) + l];
            s0 += p.x; s1 += p.y; s2 += p.z;
        }
        float dg = (float)(deg[node] + 1);
        float sc = FINAL ? rsqrtf(dg) : (1.0f / dg);
        x0 = sc * s0; x1 = sc * s1; x2 = sc * s2;
        zout[node] = make_float4(x0, x1, x2, 0.f);
    }
    if (FINAL) {                                 // OOB lanes contribute zeros
        double v[9];
        v[0] = x0; v[1] = x1; v[2] = x2;
        v[3] = (double)x0 * x0; v[4] = (double)x0 * x1; v[5] = (double)x0 * x2;
        v[6] = (double)x1 * x1; v[7] = (double)x1 * x2; v[8] = (double)x2 * x2;
#pragma unroll
        for (int jj = 0; jj < 9; jj++) {
            double s = v[jj];
            for (int m = 1; m < 64; m <<= 1) s += __shfl_xor(s, m, 64);
            if ((threadIdx.x & 63) == 0) atomicAdd(&stats[jj], s);
        }
    }
}

// ---------- graph boundaries via binary search (batch is sorted) ----------
__global__ void k_bounds(const int* __restrict__ batch, int* starts, int n) {
    int g = threadIdx.x;
    if (g <= GG) {
        int lo = 0, hi = n;
        while (lo < hi) {
            int mid = (lo + hi) >> 1;
            if (batch[mid] < g) lo = mid + 1; else hi = mid;
        }
        starts[g] = lo;
    }
}

// ---------- pooling: per (graph, channel) max/min of dot(x, W_c), fused BN0+ReLU ----------
__global__ __launch_bounds__(256) void k_pool(
    const float4* __restrict__ z, const int* __restrict__ starts,
    const float* __restrict__ lin_w,
    const float* __restrict__ bn0_g, const float* __restrict__ bn0_b,
    const double* __restrict__ stats, float* pooled, int n) {
    __shared__ float4 sh[TILE];
    int g = blockIdx.x;
    int c = blockIdx.y * 256 + threadIdx.x;

    float w0 = lin_w[c], w1 = lin_w[HID + c], w2 = lin_w[2 * HID + c];

    double invN = 1.0 / (double)n;
    double mu0 = stats[0] * invN, mu1 = stats[1] * invN, mu2 = stats[2] * invN;
    float c00 = (float)(stats[3] * invN - mu0 * mu0);
    float c01 = (float)(stats[4] * invN - mu0 * mu1);
    float c02 = (float)(stats[5] * invN - mu0 * mu2);
    float c11 = (float)(stats[6] * invN - mu1 * mu1);
    float c12 = (float)(stats[7] * invN - mu1 * mu2);
    float c22 = (float)(stats[8] * invN - mu2 * mu2);
    float meanc = (float)mu0 * w0 + (float)mu1 * w1 + (float)mu2 * w2;  // lin_b cancels in BN
    float var = c00 * w0 * w0 + c11 * w1 * w1 + c22 * w2 * w2
              + 2.f * (c01 * w0 * w1 + c02 * w0 * w2 + c12 * w1 * w2);
    var = fmaxf(var, 0.f);

    int s0 = starts[g], s1 = starts[g + 1];
    float mx = -INFINITY, mn = INFINITY;
    for (int base = s0; base < s1; base += TILE) {
        int cnt = min(TILE, s1 - base);
        __syncthreads();
        for (int j = threadIdx.x; j < cnt; j += 256) sh[j] = z[base + j];
        __syncthreads();
        for (int j = 0; j < cnt; j++) {
            float4 p = sh[j];
            float d = fmaf(p.x, w0, fmaf(p.y, w1, p.z * w2));
            mx = fmaxf(mx, d);
            mn = fminf(mn, d);
        }
    }
    float inv = rsqrtf(var + BNEPS);
    float s = bn0_g[c] * inv;
    float raw = (s >= 0.f) ? mx : mn;     // BN scale sign decides which extreme survives relu∘max
    float y = (raw - meanc) * s + bn0_b[c];
    pooled[g * HID + c] = fmaxf(y, 0.f);
}

// ---------- fused Linear + BN(over 64 rows = 1 wave) + ReLU; 1 wave per output column ----------
template <int KIN>
__global__ __launch_bounds__(64) void k_fcbn(
    const float* __restrict__ in, const float* __restrict__ W,
    const float* __restrict__ bias, const float* __restrict__ gamma,
    const float* __restrict__ beta, float* out, int Cout) {
    int c = blockIdx.x;
    int r = threadIdx.x;  // 64 rows == wave size
    const float* rowp = in + r * KIN;
    float acc = 0.f;
#pragma unroll 8
    for (int k = 0; k < KIN; k++) acc = fmaf(rowp[k], W[k * Cout + c], acc);
    float y = acc + bias[c];
    float sum = y, sq = y * y;
    for (int m = 1; m < 64; m <<= 1) {
        sum += __shfl_xor(sum, m, 64);
        sq  += __shfl_xor(sq, m, 64);
    }
    float mean = sum * (1.f / 64.f);
    float var  = fmaxf(sq * (1.f / 64.f) - mean * mean, 0.f);
    float o = (y - mean) * rsqrtf(var + BNEPS) * gamma[c] + beta[c];
    out[r * Cout + c] = fmaxf(o, 0.f);
}

// ---------- fc3 + log_softmax; 1 wave per row ----------
__global__ __launch_bounds__(64) void k_out(
    const float* __restrict__ in, const float* __restrict__ W,
    const float* __restrict__ bias, float* out) {
    int r = blockIdx.x;
    int c = threadIdx.x;
    bool act = c < NCLS;
    float z = -INFINITY;
    if (act) {
        const float* rowp = in + r * H2;
        float acc = 0.f;
#pragma unroll 8
        for (int k = 0; k < H2; k++) acc = fmaf(rowp[k], W[k * NCLS + c], acc);
        z = acc + bias[c];
    }
    float mx = z;
    for (int m = 1; m < 64; m <<= 1) mx = fmaxf(mx, __shfl_xor(mx, m, 64));
    float ex = act ? expf(z - mx) : 0.f;
    float se = ex;
    for (int m = 1; m < 64; m <<= 1) se += __shfl_xor(se, m, 64);
    if (act) out[r * NCLS + c] = z - mx - logf(se);
}

extern "C" void kernel_launch(void* const* d_in, const int* in_sizes, int n_in,
                              void* d_out, int out_size, void* d_ws, size_t ws_size,
                              hipStream_t stream) {
    const float* pos   = (const float*)d_in[0];
    const int*   ei    = (const int*)d_in[1];   // [2,E]: rows at [0,E), cols at [E,2E)
    const int*   batch = (const int*)d_in[2];
    const float* lin_w = (const float*)d_in[3];
    // d_in[4] lin_b cancels in BN0 centering
    const float* bn0_g = (const float*)d_in[5];
    const float* bn0_b = (const float*)d_in[6];
    const float* fc1_w = (const float*)d_in[7];
    const float* fc1_b = (const float*)d_in[8];
    const float* bn1_g = (const float*)d_in[9];
    const float* bn1_b = (const float*)d_in[10];
    const float* fc2_w = (const float*)d_in[11];
    const float* fc2_b = (const float*)d_in[12];
    const float* bn2_g = (const float*)d_in[13];
    const float* bn2_b = (const float*)d_in[14];
    const float* fc3_w = (const float*)d_in[15];
    const float* fc3_b = (const float*)d_in[16];

    int n = in_sizes[0] / 3;
    int e = in_sizes[1] / 2;
    int nds = cdiv(n, DSUP);       // 196 for n=100000
    int nt  = cdiv(n, STILE);      // 98
    int csz = cdiv(nt, TCH);       // 14 tiles per chunk

    auto align256 = [](size_t x) { return (x + 255) & ~(size_t)255; };
    char* w = (char*)d_ws;
    int*    blockHist = (int*)w;    w += align256((size_t)BPART * nds * 4);
    int*    blockOff  = (int*)w;    w += align256((size_t)BPART * nds * 4);
    int*    bucketSt  = (int*)w;    w += align256((size_t)(nds + 1) * 4);
    int*    cellPtr   = (int*)w;    w += align256((size_t)nds * (nt + 1) * 4);
    int*    deg       = (int*)w;    w += align256((size_t)n * 4);
    int*    ebuf1     = (int*)w;    w += align256((size_t)e * 4);
    int*    ebuf2     = (int*)w;    w += align256((size_t)e * 4);
    float4* partial   = (float4*)w; w += align256((size_t)TCH * nds * DSUP * 16);
    float4* za        = (float4*)w; w += align256((size_t)n * 16);
    float4* zb        = (float4*)w; w += align256((size_t)n * 16);
    double* stats     = (double*)w; w += align256(9 * sizeof(double));
    int*    starts    = (int*)w;    w += align256((GG + 1) * 4);
    float*  pooled    = (float*)w;  w += align256((size_t)GG * HID * 4);
    float*  h1        = (float*)w;  w += align256((size_t)GG * H1 * 4);
    float*  h2        = (float*)w;  w += align256((size_t)GG * H2 * 4);

    (void)hipMemsetAsync(stats, 0, 9 * sizeof(double), stream);

    const int* erow = ei;
    const int* ecol = ei + e;

    k_hista<<<BPART, 1024, 0, stream>>>(ecol, blockHist, e, nds);
    k_scan <<<1, 256, 0, stream>>>(blockHist, blockOff, bucketSt, e, nds);
    k_scat <<<BPART, 1024, 0, stream>>>(erow, ecol, blockOff, bucketSt, ebuf1, e, nds);
    k_tsort<<<nds, 512, 0, stream>>>(bucketSt, ebuf1, ebuf2, cellPtr, deg, pos, za, n, nt);

    int gn = cdiv(n, 256);
    dim3 gp(nds, TCH);
    // K=5 passes, double-buffered: za->zb->za->zb->za->zb (final in zb)
    k_gpart<<<gp, 512, 0, stream>>>(ebuf2, cellPtr, za, partial, n, nt, csz, nds);
    k_reduce<false><<<gn, 256, 0, stream>>>(partial, za, deg, zb, stats, n, nds, TCH);
    k_gpart<<<gp, 512, 0, stream>>>(ebuf2, cellPtr, zb, partial, n, nt, csz, nds);
    k_reduce<false><<<gn, 256, 0, stream>>>(partial, zb, deg, za, stats, n, nds, TCH);
    k_gpart<<<gp, 512, 0, stream>>>(ebuf2, cellPtr, za, partial, n, nt, csz, nds);
    k_reduce<false><<<gn, 256, 0, stream>>>(partial, za, deg, zb, stats, n, nds, TCH);
    k_gpart<<<gp, 512, 0, stream>>>(ebuf2, cellPtr, zb, partial, n, nt, csz, nds);
    k_reduce<false><<<gn, 256, 0, stream>>>(partial, zb, deg, za, stats, n, nds, TCH);
    k_gpart<<<gp, 512, 0, stream>>>(ebuf2, cellPtr, za, partial, n, nt, csz, nds);
    k_reduce<true ><<<gn, 256, 0, stream>>>(partial, za, deg, zb, stats, n, nds, TCH);

    k_bounds<<<1, 128, 0, stream>>>(batch, starts, n);
    k_pool<<<dim3(GG, HID / 256), 256, 0, stream>>>(zb, starts, lin_w, bn0_g, bn0_b, stats, pooled, n);
    k_fcbn<HID><<<H1, 64, 0, stream>>>(pooled, fc1_w, fc1_b, bn1_g, bn1_b, h1, H1);
    k_fcbn<H1><<<H2, 64, 0, stream>>>(h1, fc2_w, fc2_b, bn2_g, bn2_b, h2, H2);
    k_out<<<GG, 64, 0, stream>>>(h2, fc3_w, fc3_b, (float*)d_out);
}

// Round 12
// 700.264 us; speedup vs baseline: 1.9287x; 1.2014x over previous
//
#include <hip/hip_runtime.h>
#include <math.h>

#define HID    1024
#define GG     64
#define KPROP  5
#define H1     512
#define H2     256
#define NCLS   40
#define BNEPS  1e-5f
#define TILE   2048
#define BPART  128      // partition blocks for histogram/scatter
#define DSUP   512      // dst nodes per bucket
#define DSH    9
#define STILE  1024     // src nodes per LDS tile
#define SSH    10
#define TCH    7        // tile-chunks per bucket (parallelism multiplier)
#define MAXNDS 256      // supports n <= 131072
#define MAXNT  128

__host__ __device__ static inline int cdiv(int a, int b) { return (a + b - 1) / b; }

// ---------- Pass A: per-partition histogram over dst buckets ----------
__global__ __launch_bounds__(1024) void k_hista(const int* __restrict__ col,
                                                int* __restrict__ blockHist,
                                                int e, int nds) {
    __shared__ int h[MAXNDS];
    if (threadIdx.x < nds) h[threadIdx.x] = 0;
    __syncthreads();
    int chunk = cdiv(e, gridDim.x);
    int s = blockIdx.x * chunk, t = min(e, s + chunk);
    for (int i = s + threadIdx.x; i < t; i += 1024) atomicAdd(&h[col[i] >> DSH], 1);
    __syncthreads();
    if (threadIdx.x < nds) blockHist[blockIdx.x * nds + threadIdx.x] = h[threadIdx.x];
}

// ---------- Pass B: per-(partition,bucket) offsets + bucket starts ----------
__global__ __launch_bounds__(256) void k_scan(const int* __restrict__ blockHist,
                                              int* __restrict__ blockOff,
                                              int* __restrict__ bucketStart,
                                              int e, int nds) {
    __shared__ int tot[MAXNDS];
    int bin = threadIdx.x;
    if (bin < nds) {
        int s = 0;
        for (int p = 0; p < BPART; p++) {
            blockOff[p * nds + bin] = s;    // coalesced across threads
            s += blockHist[p * nds + bin];
        }
        tot[bin] = s;
    }
    __syncthreads();
    if (bin == 0) {
        int acc = 0;
        for (int i = 0; i < nds; i++) { int v = tot[i]; tot[i] = acc; acc += v; }
    }
    __syncthreads();
    if (bin < nds) bucketStart[bin] = tot[bin];
    if (bin == 0) bucketStart[nds] = e;
}

// ---------- Pass C: scatter packed edges into dst-bucket order ----------
// packed: tile(7b) << 19 | src_local(10b) << 9 | dst_local(9b)
__global__ __launch_bounds__(1024) void k_scat(const int* __restrict__ row,
                                               const int* __restrict__ col,
                                               const int* __restrict__ blockOff,
                                               const int* __restrict__ bucketStart,
                                               int* __restrict__ ebuf1,
                                               int e, int nds) {
    __shared__ int c2[MAXNDS];
    if (threadIdx.x < nds) c2[threadIdx.x] = 0;
    __syncthreads();
    int chunk = cdiv(e, gridDim.x);
    int s = blockIdx.x * chunk, t = min(e, s + chunk);
    const int* boff = blockOff + blockIdx.x * nds;
    for (int i = s + threadIdx.x; i < t; i += 1024) {
        int r = row[i], c = col[i];
        int bin = c >> DSH;
        int lr = atomicAdd(&c2[bin], 1);                  // LDS atomic — cheap
        int pos = bucketStart[bin] + boff[bin] + lr;      // globally unique
        ebuf1[pos] = ((r >> SSH) << 19) | ((r & (STILE - 1)) << DSH) | (c & (DSUP - 1));
    }
}

// ---------- Pass D: per-bucket tile-sort (ebuf1 -> ebuf2) + cellPtr + deg + z0 ----------
__global__ __launch_bounds__(512) void k_tsort(const int* __restrict__ bucketStart,
                                               const int* __restrict__ ebuf1,
                                               int* __restrict__ ebuf2,
                                               int* __restrict__ cellPtr,
                                               int* __restrict__ deg,
                                               const float* __restrict__ pos,
                                               float4* __restrict__ z0,
                                               int n, int nt) {
    __shared__ int cnt[MAXNT];
    __shared__ int lptr[MAXNT + 1];
    __shared__ int dcnt[DSUP];
    int g = blockIdx.x, tid = threadIdx.x;
    if (tid < nt) cnt[tid] = 0;
    dcnt[tid] = 0;
    __syncthreads();
    int s0 = bucketStart[g], s1 = bucketStart[g + 1];
    for (int i = s0 + tid; i < s1; i += 512) {
        int v = ebuf1[i];
        atomicAdd(&cnt[v >> 19], 1);
        atomicAdd(&dcnt[v & (DSUP - 1)], 1);
    }
    __syncthreads();
    if (tid == 0) {
        int acc = 0;
        for (int i = 0; i < nt; i++) { lptr[i] = acc; acc += cnt[i]; }
        lptr[nt] = acc;
    }
    __syncthreads();
    if (tid <= nt) cellPtr[g * (nt + 1) + tid] = s0 + lptr[tid];
    int node = (g << DSH) + tid;
    if (node < n) {
        int d = dcnt[tid];
        deg[node] = d;
        float dis = rsqrtf((float)(d + 1));
        z0[node] = make_float4(dis * pos[3 * node], dis * pos[3 * node + 1],
                               dis * pos[3 * node + 2], 0.f);
    }
    if (tid < nt) cnt[tid] = 0;
    __syncthreads();
    for (int i = s0 + tid; i < s1; i += 512) {
        int v = ebuf1[i];
        int t = v >> 19;
        int r = atomicAdd(&cnt[t], 1);
        ebuf2[s0 + lptr[t] + r] = v & 0x7FFFF;   // keep src_local|dst_local
    }
}

// ---------- gather partial: (bucket, tile-chunk) blocks — tiled SpMM in LDS ----------
// acc interleaved as acc[d*3+c]: one edge's 3 atomics hit 3 distinct banks
// (stride 3 coprime with 32) instead of 3x the same bank.
__global__ __launch_bounds__(512) void k_gpart(
    const int* __restrict__ ebuf, const int* __restrict__ cellPtr,
    const float4* __restrict__ zin, float4* __restrict__ partial,
    int n, int nt, int csz, int nds) {
    __shared__ float4 zs[STILE];
    __shared__ float acc[3 * DSUP];
    int g = blockIdx.x, ci = blockIdx.y, tid = threadIdx.x;
    for (int j = tid; j < 3 * DSUP; j += 512) acc[j] = 0.f;
    const int* cp = cellPtr + g * (nt + 1);
    int t0 = ci * csz, t1 = min(nt, t0 + csz);
    for (int t = t0; t < t1; t++) {
        __syncthreads();                         // zs reuse + acc visibility
        int base = t << SSH;
        int lim = min(STILE, n - base);
        for (int j = tid; j < lim; j += 512) zs[j] = zin[base + j];
        __syncthreads();
        int cs = cp[t], ce = cp[t + 1];
        for (int j = cs + tid; j < ce; j += 512) {
            int ev = ebuf[j];                    // coalesced
            float4 v = zs[(ev >> DSH) & (STILE - 1)];  // random LDS read
            int d = (ev & (DSUP - 1)) * 3;
            atomicAdd(&acc[d + 0], v.x);
            atomicAdd(&acc[d + 1], v.y);
            atomicAdd(&acc[d + 2], v.z);
        }
    }
    __syncthreads();
    partial[((size_t)(ci * nds + g) << DSH) + tid] =
        make_float4(acc[tid * 3], acc[tid * 3 + 1], acc[tid * 3 + 2], 0.f);
}

// ---------- fold partials + self-loop + scale (no stats here anymore) ----------
template <bool FINAL>
__global__ __launch_bounds__(256) void k_reduce(
    const float4* __restrict__ partial, const float4* __restrict__ zin,
    const int* __restrict__ deg, float4* __restrict__ zout,
    int n, int nds, int tch) {
    int node = blockIdx.x * 256 + threadIdx.x;
    if (node < n) {
        int g = node >> DSH, l = node & (DSUP - 1);
        float4 zi = zin[node];                   // self loop
        float s0 = zi.x, s1 = zi.y, s2 = zi.z;
        for (int ci = 0; ci < tch; ci++) {       // coalesced within each ci
            float4 p = partial[((size_t)(ci * nds + g) << DSH) + l];
            s0 += p.x; s1 += p.y; s2 += p.z;
        }
        float dg = (float)(deg[node] + 1);
        float sc = FINAL ? rsqrtf(dg) : (1.0f / dg);
        zout[node] = make_float4(sc * s0, sc * s1, sc * s2, 0.f);
    }
}

// ---------- moments of final x: block-reduce, NO global atomics ----------
__global__ __launch_bounds__(256) void k_stats(const float4* __restrict__ x,
                                               double* __restrict__ P, int n, int nb) {
    __shared__ double red[4][9];
    int node = blockIdx.x * 256 + threadIdx.x;
    float x0 = 0.f, x1 = 0.f, x2 = 0.f;
    if (node < n) { float4 v = x[node]; x0 = v.x; x1 = v.y; x2 = v.z; }
    double v[9];
    v[0] = x0; v[1] = x1; v[2] = x2;
    v[3] = (double)x0 * x0; v[4] = (double)x0 * x1; v[5] = (double)x0 * x2;
    v[6] = (double)x1 * x1; v[7] = (double)x1 * x2; v[8] = (double)x2 * x2;
    int wave = threadIdx.x >> 6, lane = threadIdx.x & 63;
#pragma unroll
    for (int jj = 0; jj < 9; jj++) {
        double t = v[jj];
        for (int m = 1; m < 64; m <<= 1) t += __shfl_xor(t, m, 64);
        if (lane == 0) red[wave][jj] = t;
    }
    __syncthreads();
    if (threadIdx.x < 9) {
        double s = red[0][threadIdx.x] + red[1][threadIdx.x]
                 + red[2][threadIdx.x] + red[3][threadIdx.x];
        P[threadIdx.x * nb + blockIdx.x] = s;   // per-block partial, no atomics
    }
}

// ---------- fold per-block moment partials (single block) ----------
__global__ __launch_bounds__(512) void k_stats2(const double* __restrict__ P,
                                                double* __restrict__ stats, int nb) {
    __shared__ double red[8];
    int wave = threadIdx.x >> 6, lane = threadIdx.x & 63;
    for (int jj = 0; jj < 9; jj++) {
        double s = 0.0;
        for (int i = threadIdx.x; i < nb; i += 512) s += P[jj * nb + i];
        for (int m = 1; m < 64; m <<= 1) s += __shfl_xor(s, m, 64);
        if (lane == 0) red[wave] = s;
        __syncthreads();
        if (threadIdx.x == 0) {
            double t = 0.0;
            for (int w = 0; w < 8; w++) t += red[w];
            stats[jj] = t;
        }
        __syncthreads();
    }
}

// ---------- graph boundaries via binary search (batch is sorted) ----------
__global__ void k_bounds(const int* __restrict__ batch, int* starts, int n) {
    int g = threadIdx.x;
    if (g <= GG) {
        int lo = 0, hi = n;
        while (lo < hi) {
            int mid = (lo + hi) >> 1;
            if (batch[mid] < g) lo = mid + 1; else hi = mid;
        }
        starts[g] = lo;
    }
}

// ---------- pooling: per (graph, channel) max/min of dot(x, W_c), fused BN0+ReLU ----------
__global__ __launch_bounds__(256) void k_pool(
    const float4* __restrict__ z, const int* __restrict__ starts,
    const float* __restrict__ lin_w,
    const float* __restrict__ bn0_g, const float* __restrict__ bn0_b,
    const double* __restrict__ stats, float* pooled, int n) {
    __shared__ float4 sh[TILE];
    int g = blockIdx.x;
    int c = blockIdx.y * 256 + threadIdx.x;

    float w0 = lin_w[c], w1 = lin_w[HID + c], w2 = lin_w[2 * HID + c];

    double invN = 1.0 / (double)n;
    double mu0 = stats[0] * invN, mu1 = stats[1] * invN, mu2 = stats[2] * invN;
    float c00 = (float)(stats[3] * invN - mu0 * mu0);
    float c01 = (float)(stats[4] * invN - mu0 * mu1);
    float c02 = (float)(stats[5] * invN - mu0 * mu2);
    float c11 = (float)(stats[6] * invN - mu1 * mu1);
    float c12 = (float)(stats[7] * invN - mu1 * mu2);
    float c22 = (float)(stats[8] * invN - mu2 * mu2);
    float meanc = (float)mu0 * w0 + (float)mu1 * w1 + (float)mu2 * w2;  // lin_b cancels in BN
    float var = c00 * w0 * w0 + c11 * w1 * w1 + c22 * w2 * w2
              + 2.f * (c01 * w0 * w1 + c02 * w0 * w2 + c12 * w1 * w2);
    var = fmaxf(var, 0.f);

    int s0 = starts[g], s1 = starts[g + 1];
    float mx = -INFINITY, mn = INFINITY;
    for (int base = s0; base < s1; base += TILE) {
        int cnt = min(TILE, s1 - base);
        __syncthreads();
        for (int j = threadIdx.x; j < cnt; j += 256) sh[j] = z[base + j];
        __syncthreads();
        for (int j = 0; j < cnt; j++) {
            float4 p = sh[j];
            float d = fmaf(p.x, w0, fmaf(p.y, w1, p.z * w2));
            mx = fmaxf(mx, d);
            mn = fminf(mn, d);
        }
    }
    float inv = rsqrtf(var + BNEPS);
    float s = bn0_g[c] * inv;
    float raw = (s >= 0.f) ? mx : mn;     // BN scale sign decides which extreme survives relu∘max
    float y = (raw - meanc) * s + bn0_b[c];
    pooled[g * HID + c] = fmaxf(y, 0.f);
}

// ---------- fused Linear + BN(over 64 rows = 1 wave) + ReLU; 1 wave per output column ----------
template <int KIN>
__global__ __launch_bounds__(64) void k_fcbn(
    const float* __restrict__ in, const float* __restrict__ W,
    const float* __restrict__ bias, const float* __restrict__ gamma,
    const float* __restrict__ beta, float* out, int Cout) {
    int c = blockIdx.x;
    int r = threadIdx.x;  // 64 rows == wave size
    const float* rowp = in + r * KIN;
    float acc = 0.f;
#pragma unroll 8
    for (int k = 0; k < KIN; k++) acc = fmaf(rowp[k], W[k * Cout + c], acc);
    float y = acc + bias[c];
    float sum = y, sq = y * y;
    for (int m = 1; m < 64; m <<= 1) {
        sum += __shfl_xor(sum, m, 64);
        sq  += __shfl_xor(sq, m, 64);
    }
    float mean = sum * (1.f / 64.f);
    float var  = fmaxf(sq * (1.f / 64.f) - mean * mean, 0.f);
    float o = (y - mean) * rsqrtf(var + BNEPS) * gamma[c] + beta[c];
    out[r * Cout + c] = fmaxf(o, 0.f);
}

// ---------- fc3 + log_softmax; 1 wave per row ----------
__global__ __launch_bounds__(64) void k_out(
    const float* __restrict__ in, const float* __restrict__ W,
    const float* __restrict__ bias, float* out) {
    int r = blockIdx.x;
    int c = threadIdx.x;
    bool act = c < NCLS;
    float z = -INFINITY;
    if (act) {
        const float* rowp = in + r * H2;
        float acc = 0.f;
#pragma unroll 8
        for (int k = 0; k < H2; k++) acc = fmaf(rowp[k], W[k * NCLS + c], acc);
        z = acc + bias[c];
    }
    float mx = z;
    for (int m = 1; m < 64; m <<= 1) mx = fmaxf(mx, __shfl_xor(mx, m, 64));
    float ex = act ? expf(z - mx) : 0.f;
    float se = ex;
    for (int m = 1; m < 64; m <<= 1) se += __shfl_xor(se, m, 64);
    if (act) out[r * NCLS + c] = z - mx - logf(se);
}

extern "C" void kernel_launch(void* const* d_in, const int* in_sizes, int n_in,
                              void* d_out, int out_size, void* d_ws, size_t ws_size,
                              hipStream_t stream) {
    const float* pos   = (const float*)d_in[0];
    const int*   ei    = (const int*)d_in[1];   // [2,E]: rows at [0,E), cols at [E,2E)
    const int*   batch = (const int*)d_in[2];
    const float* lin_w = (const float*)d_in[3];
    // d_in[4] lin_b cancels in BN0 centering
    const float* bn0_g = (const float*)d_in[5];
    const float* bn0_b = (const float*)d_in[6];
    const float* fc1_w = (const float*)d_in[7];
    const float* fc1_b = (const float*)d_in[8];
    const float* bn1_g = (const float*)d_in[9];
    const float* bn1_b = (const float*)d_in[10];
    const float* fc2_w = (const float*)d_in[11];
    const float* fc2_b = (const float*)d_in[12];
    const float* bn2_g = (const float*)d_in[13];
    const float* bn2_b = (const float*)d_in[14];
    const float* fc3_w = (const float*)d_in[15];
    const float* fc3_b = (const float*)d_in[16];

    int n = in_sizes[0] / 3;
    int e = in_sizes[1] / 2;
    int nds = cdiv(n, DSUP);       // 196 for n=100000
    int nt  = cdiv(n, STILE);      // 98
    int csz = cdiv(nt, TCH);       // 14 tiles per chunk
    int gn  = cdiv(n, 256);        // 391

    auto align256 = [](size_t x) { return (x + 255) & ~(size_t)255; };
    char* w = (char*)d_ws;
    int*    blockHist = (int*)w;    w += align256((size_t)BPART * nds * 4);
    int*    blockOff  = (int*)w;    w += align256((size_t)BPART * nds * 4);
    int*    bucketSt  = (int*)w;    w += align256((size_t)(nds + 1) * 4);
    int*    cellPtr   = (int*)w;    w += align256((size_t)nds * (nt + 1) * 4);
    int*    deg       = (int*)w;    w += align256((size_t)n * 4);
    int*    ebuf1     = (int*)w;    w += align256((size_t)e * 4);
    int*    ebuf2     = (int*)w;    w += align256((size_t)e * 4);
    float4* partial   = (float4*)w; w += align256((size_t)TCH * nds * DSUP * 16);
    float4* za        = (float4*)w; w += align256((size_t)n * 16);
    float4* zb        = (float4*)w; w += align256((size_t)n * 16);
    double* stats     = (double*)w; w += align256(9 * sizeof(double));
    double* statP     = (double*)w; w += align256((size_t)9 * gn * 8);
    int*    starts    = (int*)w;    w += align256((GG + 1) * 4);
    float*  pooled    = (float*)w;  w += align256((size_t)GG * HID * 4);
    float*  h1        = (float*)w;  w += align256((size_t)GG * H1 * 4);
    float*  h2        = (float*)w;  w += align256((size_t)GG * H2 * 4);

    const int* erow = ei;
    const int* ecol = ei + e;

    k_hista<<<BPART, 1024, 0, stream>>>(ecol, blockHist, e, nds);
    k_scan <<<1, 256, 0, stream>>>(blockHist, blockOff, bucketSt, e, nds);
    k_scat <<<BPART, 1024, 0, stream>>>(erow, ecol, blockOff, bucketSt, ebuf1, e, nds);
    k_tsort<<<nds, 512, 0, stream>>>(bucketSt, ebuf1, ebuf2, cellPtr, deg, pos, za, n, nt);

    dim3 gp(nds, TCH);
    // K=5 passes, double-buffered: za->zb->za->zb->za->zb (final in zb)
    k_gpart<<<gp, 512, 0, stream>>>(ebuf2, cellPtr, za, partial, n, nt, csz, nds);
    k_reduce<false><<<gn, 256, 0, stream>>>(partial, za, deg, zb, n, nds, TCH);
    k_gpart<<<gp, 512, 0, stream>>>(ebuf2, cellPtr, zb, partial, n, nt, csz, nds);
    k_reduce<false><<<gn, 256, 0, stream>>>(partial, zb, deg, za, n, nds, TCH);
    k_gpart<<<gp, 512, 0, stream>>>(ebuf2, cellPtr, za, partial, n, nt, csz, nds);
    k_reduce<false><<<gn, 256, 0, stream>>>(partial, za, deg, zb, n, nds, TCH);
    k_gpart<<<gp, 512, 0, stream>>>(ebuf2, cellPtr, zb, partial, n, nt, csz, nds);
    k_reduce<false><<<gn, 256, 0, stream>>>(partial, zb, deg, za, n, nds, TCH);
    k_gpart<<<gp, 512, 0, stream>>>(ebuf2, cellPtr, za, partial, n, nt, csz, nds);
    k_reduce<true ><<<gn, 256, 0, stream>>>(partial, za, deg, zb, n, nds, TCH);

    k_stats <<<gn, 256, 0, stream>>>(zb, statP, n, gn);
    k_stats2<<<1, 512, 0, stream>>>(statP, stats, gn);

    k_bounds<<<1, 128, 0, stream>>>(batch, starts, n);
    k_pool<<<dim3(GG, HID / 256), 256, 0, stream>>>(zb, starts, lin_w, bn0_g, bn0_b, stats, pooled, n);
    k_fcbn<HID><<<H1, 64, 0, stream>>>(pooled, fc1_w, fc1_b, bn1_g, bn1_b, h1, H1);
    k_fcbn<H1><<<H2, 64, 0, stream>>>(h1, fc2_w, fc2_b, bn2_g, bn2_b, h2, H2);
    k_out<<<GG, 64, 0, stream>>>(h2, fc3_w, fc3_b, (float*)d_out);
}